// Round 4
// baseline (329.196 us; speedup 1.0000x reference)
//
#include <hip/hip_runtime.h>

#define N_ROWS   524288
#define W_BINS   101
#define EPS_F    1e-3f
#define RPB      64                    // rows per tile = 1 row per lane
#define NTILES   (N_ROWS / RPB)        // 8192 tiles
#define GRID     1024                  // persistent blocks
#define TPB      (NTILES / GRID)       // 8 tiles per block
#define TILE_F   (RPB * W_BINS)        // 6464 floats = 25,856 B per tile buffer

typedef const float __attribute__((address_space(1)))* gfp_t;
typedef float __attribute__((address_space(3)))* sfp_t;
typedef const int __attribute__((address_space(1)))* gip_t;
typedef int __attribute__((address_space(3)))* sip_t;

// Raw waitcnt with memory clobber: compiler may not hoist LDS reads above it,
// and emits no vmcnt waits of its own (no VGPR global loads exist in the loop).
#define WAIT_VM27() asm volatile("s_waitcnt vmcnt(27)" ::: "memory")
#define WAIT_VM0()  asm volatile("s_waitcnt vmcnt(0)"  ::: "memory")

// One DMA batch = exactly 27 vm ops: 25 full-wave 16B + 1 16-lane 16B tail
// for the 6464-float tile, + 1 16-lane 16B op for the 64 targets.
__device__ __forceinline__ void dma_batch(const float* gsrc, float* lds,
                                          const int* gt, int* lt, int lane) {
    #pragma unroll
    for (int q = 0; q < 25; ++q) {
        __builtin_amdgcn_global_load_lds((gfp_t)(gsrc + q * 256 + lane * 4),
                                         (sfp_t)(lds + q * 256), 16, 0, 0);
    }
    if (lane < 16) {
        __builtin_amdgcn_global_load_lds((gfp_t)(gsrc + 6400 + lane * 4),
                                         (sfp_t)(lds + 6400), 16, 0, 0);
        __builtin_amdgcn_global_load_lds((gip_t)(gt + lane * 4),
                                         (sip_t)lt, 16, 0, 0);
    }
}

// Persistent blocks, 1 wave each, double-buffered tile DMA. While tile k is
// computed, tile k+1's 27 DMA ops stream in the background (round-3 showed
// the vmcnt(0)-per-tile structure leaves HBM 90% idle at 6 waves/CU).
__global__ __launch_bounds__(64) void mrl_main(const float* __restrict__ x,
                                               const int* __restrict__ tgt,
                                               float4* __restrict__ partial) {
    __shared__ float sm[2][TILE_F];
    __shared__ int   ts[2][RPB];
    const int lane = threadIdx.x;

    int tile = blockIdx.x;
    dma_batch(x + (size_t)tile * TILE_F, sm[0], tgt + tile * RPB, ts[0], lane);

    float racc = 0.f, sqac = 0.f, kfac = 0.f;
    int buf = 0;

    #pragma unroll 1
    for (int j = 0; j < TPB; ++j) {
        if (j + 1 < TPB) {
            const int nt = tile + GRID;
            dma_batch(x + (size_t)nt * TILE_F, sm[buf ^ 1],
                      tgt + nt * RPB, ts[buf ^ 1], lane);
            WAIT_VM27();              // tile j's 27 ops retired; j+1 in flight
        } else {
            WAIT_VM0();
        }

        const float* r = sm[buf] + lane * W_BINS;  // stride 101: 2-way banks = free
        const int    t = ts[buf][lane];

        // Pass 1: sum(e), sum(e*a). No max-subtraction (std-normal inputs,
        // fp32 exp safe). Dual accumulators break the serial add chain.
        float se0 = 0.f, se1 = 0.f, sa0 = 0.f, sa1 = 0.f;
        #pragma unroll
        for (int i = 0; i < 100; i += 2) {
            float e0 = __expf(r[i]);
            float e1 = __expf(r[i + 1]);
            se0 += e0; sa0 += e0 * (float)i;
            se1 += e1; sa1 += e1 * (float)(i + 1);
        }
        {
            float e = __expf(r[100]);
            se0 += e; sa0 += e * 100.0f;
        }
        const float se  = se0 + se1;
        const float sea = sa0 + sa1;

        const float egt = __expf(r[t]);
        const float inv = __builtin_amdgcn_rcpf(se);
        const float d   = sea * inv - (float)t;
        sqac += d * d;

        // Pass 2: residue + K. e-space compare (scale-invariant):
        // e_i < e_gt <=> p_i < p_gt. Masked bins contribute -(EPS)log(EPS),
        // matching the reference; i==t is never lt -> counted in K.
        float rc0 = 0.f, rc1 = 0.f;
        int   kk  = 0;
        #pragma unroll
        for (int i = 0; i < 100; i += 2) {
            float e0 = __expf(r[i]);
            float e1 = __expf(r[i + 1]);
            bool  l0 = e0 < egt, l1 = e1 < egt;
            float q0 = (l0 ? e0 * inv : 0.f) + EPS_F;
            float q1 = (l1 ? e1 * inv : 0.f) + EPS_F;
            rc0 -= q0 * __logf(q0);
            rc1 -= q1 * __logf(q1);
            kk  += (l0 ? 0 : 1) + (l1 ? 0 : 1);
        }
        {
            float e = __expf(r[100]);
            bool  l = e < egt;
            float q = (l ? e * inv : 0.f) + EPS_F;
            rc0 -= q * __logf(q);
            kk  += l ? 0 : 1;
        }
        racc += rc0 + rc1;
        kfac += (float)kk;            // <= 808 total: exact in float

        tile += GRID;
        buf ^= 1;
    }

    // Wave butterfly over the 3 per-lane scalars (once per block).
    #pragma unroll
    for (int off = 32; off >= 1; off >>= 1) {
        sqac += __shfl_xor(sqac, off);
        racc += __shfl_xor(racc, off);
        kfac += __shfl_xor(kfac, off);
    }
    if (lane == 0) {
        partial[blockIdx.x] = make_float4(sqac, racc, kfac, 0.0f);
    }
}

__global__ __launch_bounds__(256) void mrl_reduce(const float4* __restrict__ partial,
                                                  float* __restrict__ out) {
    double s = 0.0, r = 0.0, k = 0.0;
    for (int i = threadIdx.x; i < GRID; i += 256) {
        float4 v = partial[i];
        s += (double)v.x; r += (double)v.y; k += (double)v.z;
    }
    #pragma unroll
    for (int off = 32; off >= 1; off >>= 1) {
        s += __shfl_xor(s, off);
        r += __shfl_xor(r, off);
        k += __shfl_xor(k, off);
    }
    __shared__ double sd[12];
    const int w = threadIdx.x >> 6;
    if ((threadIdx.x & 63) == 0) { sd[w * 3 + 0] = s; sd[w * 3 + 1] = r; sd[w * 3 + 2] = k; }
    __syncthreads();
    if (threadIdx.x == 0) {
        double S = sd[0] + sd[3] + sd[6] + sd[9];
        double R = sd[1] + sd[4] + sd[7] + sd[10];
        double K = sd[2] + sd[5] + sd[8] + sd[11];
        const double n = (double)N_ROWS;
        out[0] = (float)(0.1  * (S / n));   // LAMBDA_1 * mean_loss (0.2 * 0.5)
        out[1] = (float)(0.05 * (R / n));   // LAMBDA_2 * residue_loss
        out[2] = (float)(K / n);            // batch_average_K
    }
}

extern "C" void kernel_launch(void* const* d_in, const int* in_sizes, int n_in,
                              void* d_out, int out_size, void* d_ws, size_t ws_size,
                              hipStream_t stream) {
    const float* x   = (const float*)d_in[0];
    const int*   tgt = (const int*)d_in[1];
    float*  out     = (float*)d_out;
    float4* partial = (float4*)d_ws;    // 1024 * 16 B = 16 KiB

    mrl_main<<<GRID, 64, 0, stream>>>(x, tgt, partial);
    mrl_reduce<<<1, 256, 0, stream>>>(partial, out);
}

// Round 5
// 322.928 us; speedup vs baseline: 1.0194x; 1.0194x over previous
//
#include <hip/hip_runtime.h>

#define N_ROWS   524288
#define W_BINS   101
#define EPS_F    1e-3f
#define NTHREADS 256
#define NBLK     (N_ROWS / NTHREADS)   // 2048 blocks
#define NWAVES   (N_ROWS / 64)         // 8192 wave partials

// One thread = one full row, register-resident. No LDS, no syncthreads, no
// atomics. Rounds 1-4 all starved the memory system (~850 GB/s) by having
// too few independent streams per CU (cross-lane chains / single-wave
// blocks / serialized DMA drains). Here each wave has ~26 KB of independent
// dword loads in flight and ~12 waves/CU provide TLP.
// __launch_bounds__(256,3): cap VGPR at ~170 so the ~110-live register row
// (x[i] dies into e[i]) still allows 3 waves/SIMD = 12 waves/CU.
__global__ __launch_bounds__(256, 3) void mrl_main(const float* __restrict__ x,
                                                   const int* __restrict__ tgt,
                                                   float4* __restrict__ partial) {
    const int row = blockIdx.x * NTHREADS + threadIdx.x;
    const float* __restrict__ r = x + (size_t)row * W_BINS;

    const int   t  = tgt[row];     // coalesced
    const float xt = r[t];         // issue early; line L1-hot by the time it's used

    // Pass 1: e_i = exp(x_i) kept in registers; sum(e), sum(e*a).
    // No max-subtraction: std-normal inputs, fp32 exp safe; softmax is
    // shift-invariant so the result matches the reference to rounding.
    float e[W_BINS];
    float se0 = 0.f, se1 = 0.f, sa0 = 0.f, sa1 = 0.f;
    #pragma unroll
    for (int i = 0; i < 100; i += 2) {
        float v0 = r[i];
        float v1 = r[i + 1];
        float E0 = __expf(v0);
        float E1 = __expf(v1);
        e[i] = E0;     e[i + 1] = E1;
        se0 += E0;     sa0 += E0 * (float)i;
        se1 += E1;     sa1 += E1 * (float)(i + 1);
    }
    {
        float E = __expf(r[100]);
        e[100] = E;
        se0 += E; sa0 += E * 100.0f;
    }
    const float se  = se0 + se1;
    const float sea = sa0 + sa1;

    const float egt = __expf(xt);  // bit-identical to e[t]
    const float inv = __builtin_amdgcn_rcpf(se);
    const float d   = sea * inv - (float)t;
    float sq = d * d;

    // Pass 2 (register-resident): residue + K. e-space compare is
    // scale-invariant (e_i < e_gt <=> p_i < p_gt). Masked-out bins
    // contribute -(EPS)*log(EPS), matching the reference; i==t is never
    // lt -> counted in K.
    float rc0 = 0.f, rc1 = 0.f;
    int   kk  = 0;
    #pragma unroll
    for (int i = 0; i < 100; i += 2) {
        bool  l0 = e[i]     < egt;
        bool  l1 = e[i + 1] < egt;
        float q0 = (l0 ? e[i]     * inv : 0.f) + EPS_F;
        float q1 = (l1 ? e[i + 1] * inv : 0.f) + EPS_F;
        rc0 -= q0 * __logf(q0);
        rc1 -= q1 * __logf(q1);
        kk  += (l0 ? 0 : 1) + (l1 ? 0 : 1);
    }
    {
        bool  l = e[100] < egt;
        float q = (l ? e[100] * inv : 0.f) + EPS_F;
        rc0 -= q * __logf(q);
        kk  += l ? 0 : 1;
    }
    float rc = rc0 + rc1;
    float kf = (float)kk;          // <= 101: exact in float

    // Per-wave butterfly; lane 0 stores the wave's partial. No LDS needed.
    #pragma unroll
    for (int off = 32; off >= 1; off >>= 1) {
        sq += __shfl_xor(sq, off);
        rc += __shfl_xor(rc, off);
        kf += __shfl_xor(kf, off);
    }
    if ((threadIdx.x & 63) == 0) {
        partial[row >> 6] = make_float4(sq, rc, kf, 0.0f);
    }
}

__global__ __launch_bounds__(256) void mrl_reduce(const float4* __restrict__ partial,
                                                  float* __restrict__ out) {
    double s = 0.0, r = 0.0, k = 0.0;
    for (int i = threadIdx.x; i < NWAVES; i += 256) {
        float4 v = partial[i];
        s += (double)v.x; r += (double)v.y; k += (double)v.z;
    }
    #pragma unroll
    for (int off = 32; off >= 1; off >>= 1) {
        s += __shfl_xor(s, off);
        r += __shfl_xor(r, off);
        k += __shfl_xor(k, off);
    }
    __shared__ double sd[12];
    const int w = threadIdx.x >> 6;
    if ((threadIdx.x & 63) == 0) { sd[w * 3 + 0] = s; sd[w * 3 + 1] = r; sd[w * 3 + 2] = k; }
    __syncthreads();
    if (threadIdx.x == 0) {
        double S = sd[0] + sd[3] + sd[6] + sd[9];
        double R = sd[1] + sd[4] + sd[7] + sd[10];
        double K = sd[2] + sd[5] + sd[8] + sd[11];
        const double n = (double)N_ROWS;
        out[0] = (float)(0.1  * (S / n));   // LAMBDA_1 * mean_loss (0.2 * 0.5)
        out[1] = (float)(0.05 * (R / n));   // LAMBDA_2 * residue_loss
        out[2] = (float)(K / n);            // batch_average_K
    }
}

extern "C" void kernel_launch(void* const* d_in, const int* in_sizes, int n_in,
                              void* d_out, int out_size, void* d_ws, size_t ws_size,
                              hipStream_t stream) {
    const float* x   = (const float*)d_in[0];
    const int*   tgt = (const int*)d_in[1];
    float*  out     = (float*)d_out;
    float4* partial = (float4*)d_ws;    // 8192 * 16 B = 128 KiB

    mrl_main<<<NBLK, NTHREADS, 0, stream>>>(x, tgt, partial);
    mrl_reduce<<<1, 256, 0, stream>>>(partial, out);
}

// Round 6
// 306.956 us; speedup vs baseline: 1.0725x; 1.0520x over previous
//
#include <hip/hip_runtime.h>

#define N_ROWS   524288
#define W_BINS   101
#define EPS_F    1e-3f
#define RPB      64                    // rows per block = 1 row per lane
#define NBLK     (N_ROWS / RPB)        // 8192 blocks, 1 wave each
#define TILE_F   (RPB * W_BINS)        // 6464 floats = 25,856 B (16B-aligned/block)
#define TILE_V4  (TILE_F / 4)          // 1616 float4

// r5 post-mortem: one-row-per-thread global loads are fully divergent (64
// lines per wave instruction) -> L1 transaction-rate bound (~118 us). Fix:
// stage the 64-row tile into LDS with coalesced float4 loads (16x fewer
// line transactions), then compute one row per lane from LDS. e[] stays in
// registers so exp() runs once per element (r3 ran it twice). 6 blocks/CU
// (LDS-limited) provide the load/compute stagger; the compiler's
// fine-grained vmcnt before each ds_write keeps ~25 loads in flight.
__global__ __launch_bounds__(64) void mrl_main(const float* __restrict__ x,
                                               const int* __restrict__ tgt,
                                               float4* __restrict__ partial) {
    __shared__ float sm[TILE_F];
    const int lane = threadIdx.x;

    const float4* __restrict__ g  = (const float4*)(x + (size_t)blockIdx.x * TILE_F);
    float4* __restrict__       s4 = (float4*)sm;

    // Coalesced staging: 25 full-wave float4 copies + 16-lane tail.
    #pragma unroll
    for (int q = 0; q < 25; ++q) {
        s4[q * 64 + lane] = g[q * 64 + lane];
    }
    if (lane < 16) {
        s4[1600 + lane] = g[1600 + lane];
    }

    const int t = tgt[blockIdx.x * RPB + lane];   // coalesced, 1 line / 16 lanes

    __syncthreads();   // single-wave block: just the waitcnt drain + cheap barrier

    // Row base: word-stride 101 across lanes; 101 mod 32 = 5, gcd(5,32)=1 ->
    // each bank hit exactly 2x per wave access = free (m136).
    const int rb = lane * W_BINS;

    // Pass 1: e_i = exp(x_i) into registers; sum(e), sum(e*a).
    // No max-subtraction: std-normal inputs, fp32 exp safe; softmax is
    // shift-invariant so results match the reference to rounding.
    float e[W_BINS];
    float se0 = 0.f, se1 = 0.f, sa0 = 0.f, sa1 = 0.f;
    #pragma unroll
    for (int i = 0; i < 100; i += 2) {
        float E0 = __expf(sm[rb + i]);
        float E1 = __expf(sm[rb + i + 1]);
        e[i] = E0;     e[i + 1] = E1;
        se0 += E0;     sa0 += E0 * (float)i;
        se1 += E1;     sa1 += E1 * (float)(i + 1);
    }
    {
        float E = __expf(sm[rb + 100]);
        e[100] = E;
        se0 += E; sa0 += E * 100.0f;
    }
    const float se  = se0 + se1;
    const float sea = sa0 + sa1;

    const float egt = __expf(sm[rb + t]);   // dynamic LDS read; bit-identical to e[t]
    const float inv = __builtin_amdgcn_rcpf(se);
    const float d   = sea * inv - (float)t;
    float sq = d * d;

    // Pass 2 (register-only): residue + K. e-space compare is scale-invariant
    // (e_i < e_gt <=> p_i < p_gt). Masked-out bins contribute -(EPS)log(EPS),
    // matching the reference; i==t is never lt -> counted in K.
    float rc0 = 0.f, rc1 = 0.f;
    int   kk  = 0;
    #pragma unroll
    for (int i = 0; i < 100; i += 2) {
        bool  l0 = e[i]     < egt;
        bool  l1 = e[i + 1] < egt;
        float q0 = (l0 ? e[i]     * inv : 0.f) + EPS_F;
        float q1 = (l1 ? e[i + 1] * inv : 0.f) + EPS_F;
        rc0 -= q0 * __logf(q0);
        rc1 -= q1 * __logf(q1);
        kk  += (l0 ? 0 : 1) + (l1 ? 0 : 1);
    }
    {
        bool  l = e[100] < egt;
        float q = (l ? e[100] * inv : 0.f) + EPS_F;
        rc0 -= q * __logf(q);
        kk  += l ? 0 : 1;
    }
    float rc = rc0 + rc1;
    float kf = (float)kk;              // <= 101: exact in float

    // Wave butterfly over the 3 per-row scalars; lane 0 stores the partial.
    #pragma unroll
    for (int off = 32; off >= 1; off >>= 1) {
        sq += __shfl_xor(sq, off);
        rc += __shfl_xor(rc, off);
        kf += __shfl_xor(kf, off);
    }
    if (lane == 0) {
        partial[blockIdx.x] = make_float4(sq, rc, kf, 0.0f);
    }
}

__global__ __launch_bounds__(256) void mrl_reduce(const float4* __restrict__ partial,
                                                  float* __restrict__ out) {
    double s = 0.0, r = 0.0, k = 0.0;
    for (int i = threadIdx.x; i < NBLK; i += 256) {
        float4 v = partial[i];
        s += (double)v.x; r += (double)v.y; k += (double)v.z;
    }
    #pragma unroll
    for (int off = 32; off >= 1; off >>= 1) {
        s += __shfl_xor(s, off);
        r += __shfl_xor(r, off);
        k += __shfl_xor(k, off);
    }
    __shared__ double sd[12];
    const int w = threadIdx.x >> 6;
    if ((threadIdx.x & 63) == 0) { sd[w * 3 + 0] = s; sd[w * 3 + 1] = r; sd[w * 3 + 2] = k; }
    __syncthreads();
    if (threadIdx.x == 0) {
        double S = sd[0] + sd[3] + sd[6] + sd[9];
        double R = sd[1] + sd[4] + sd[7] + sd[10];
        double K = sd[2] + sd[5] + sd[8] + sd[11];
        const double n = (double)N_ROWS;
        out[0] = (float)(0.1  * (S / n));   // LAMBDA_1 * mean_loss (0.2 * 0.5)
        out[1] = (float)(0.05 * (R / n));   // LAMBDA_2 * residue_loss
        out[2] = (float)(K / n);            // batch_average_K
    }
}

extern "C" void kernel_launch(void* const* d_in, const int* in_sizes, int n_in,
                              void* d_out, int out_size, void* d_ws, size_t ws_size,
                              hipStream_t stream) {
    const float* x   = (const float*)d_in[0];
    const int*   tgt = (const int*)d_in[1];
    float*  out     = (float*)d_out;
    float4* partial = (float4*)d_ws;    // 8192 * 16 B = 128 KiB

    mrl_main<<<NBLK, RPB, 0, stream>>>(x, tgt, partial);
    mrl_reduce<<<1, 256, 0, stream>>>(partial, out);
}